// Round 3
// baseline (466.191 us; speedup 1.0000x reference)
//
#include <hip/hip_runtime.h>
#include <hip/hip_bf16.h>

// ColBERT MaxSim: B=64, SQ=128, SD=1024, H=768, D=128
#define NB 64
#define SQL 128
#define SDL 1024
#define HH 768
#define DD 128

typedef __attribute__((ext_vector_type(8))) short short8;
typedef __attribute__((ext_vector_type(4))) float f32x4;

__device__ __forceinline__ unsigned short bf16r(float f) {
    unsigned int u = __builtin_bit_cast(unsigned int, f);
    u += 0x7FFFu + ((u >> 16) & 1u);
    return (unsigned short)(u >> 16);
}

__device__ __forceinline__ short8 cvt8(float4 a, float4 b) {
    short8 s;
    s[0] = (short)bf16r(a.x); s[1] = (short)bf16r(a.y);
    s[2] = (short)bf16r(a.z); s[3] = (short)bf16r(a.w);
    s[4] = (short)bf16r(b.x); s[5] = (short)bf16r(b.y);
    s[6] = (short)bf16r(b.z); s[7] = (short)bf16r(b.w);
    return s;
}

// ---------------- kernel 1: W fp32 -> bf16 ----------------
__global__ __launch_bounds__(256) void k_wconv(const float* __restrict__ W,
                                               unsigned short* __restrict__ Wb) {
    int i = blockIdx.x * 256 + threadIdx.x;
    float4 v = reinterpret_cast<const float4*>(W)[i];
    ushort4 o;
    o.x = bf16r(v.x); o.y = bf16r(v.y); o.z = bf16r(v.z); o.w = bf16r(v.w);
    reinterpret_cast<ushort4*>(Wb)[i] = o;
}

// ---------------- kernel 2: project + L2-normalize ----------------
// 16 tokens per wave (1 row per l15 lane), full D=128 per wave, depth-3
// register prefetch of the hidden row. Grid 1152 blocks x 4 waves.
__global__ __launch_bounds__(256, 4) void k_project(
        const float* __restrict__ qh, const int* __restrict__ qm,
        const float* __restrict__ dh, const int* __restrict__ dm,
        const unsigned short* __restrict__ Wb,
        unsigned short* __restrict__ qe, unsigned short* __restrict__ de) {
    int bx = blockIdx.x;          // 1152 = 64 b * 9 segs * 2 halves
    int b = bx / 18;
    int r = bx % 18;
    int seg = r >> 1;
    int half = r & 1;
    const float* src;
    const int* mask;
    unsigned short* dst;
    if (seg == 0) {
        src = qh + (size_t)b * SQL * HH;
        mask = qm + (size_t)b * SQL;
        dst = qe + (size_t)b * SQL * DD;
    } else {
        size_t off = (size_t)(seg - 1) * 128;
        src = dh + ((size_t)b * SDL + off) * HH;
        mask = dm + (size_t)b * SDL + off;
        dst = de + ((size_t)b * SDL + off) * DD;
    }

    int lane = threadIdx.x & 63;
    int w = threadIdx.x >> 6;
    int l15 = lane & 15;
    int lg = lane >> 4;
    int tok = half * 64 + w * 16 + l15;   // token within the 128-token segment

    const float* rp = src + (size_t)tok * HH + lg * 8;  // lane's k-base

    f32x4 acc[8];
#pragma unroll
    for (int dt = 0; dt < 8; ++dt) acc[dt] = (f32x4){0.f, 0.f, 0.f, 0.f};

    // prefetch k-steps 0,1,2 (each k-step: 8 floats = 2 float4 per lane)
    float4 pa0 = *reinterpret_cast<const float4*>(rp);
    float4 pb0 = *reinterpret_cast<const float4*>(rp + 4);
    float4 pa1 = *reinterpret_cast<const float4*>(rp + 32);
    float4 pb1 = *reinterpret_cast<const float4*>(rp + 36);
    float4 pa2 = *reinterpret_cast<const float4*>(rp + 64);
    float4 pb2 = *reinterpret_cast<const float4*>(rp + 68);

    for (int ks = 0; ks < 24; ks += 3) {
        // ---- sub-step 0: consume (pa0,pb0) for k-step ks, prefetch ks+3 ----
        {
            short8 h = cvt8(pa0, pb0);
            int nk = ks + 3;
            const float* np = rp + (size_t)(nk < 24 ? nk : 0) * 32;
            pa0 = *reinterpret_cast<const float4*>(np);
            pb0 = *reinterpret_cast<const float4*>(np + 4);
            int k0 = ks * 32 + lg * 8;
#pragma unroll
            for (int dt = 0; dt < 8; ++dt) {
                short8 wf = *reinterpret_cast<const short8*>(Wb + (size_t)(dt * 16 + l15) * HH + k0);
                acc[dt] = __builtin_amdgcn_mfma_f32_16x16x32_bf16(wf, h, acc[dt], 0, 0, 0);
            }
        }
        // ---- sub-step 1 ----
        {
            short8 h = cvt8(pa1, pb1);
            int nk = ks + 4;
            const float* np = rp + (size_t)(nk < 24 ? nk : 0) * 32;
            pa1 = *reinterpret_cast<const float4*>(np);
            pb1 = *reinterpret_cast<const float4*>(np + 4);
            int k0 = (ks + 1) * 32 + lg * 8;
#pragma unroll
            for (int dt = 0; dt < 8; ++dt) {
                short8 wf = *reinterpret_cast<const short8*>(Wb + (size_t)(dt * 16 + l15) * HH + k0);
                acc[dt] = __builtin_amdgcn_mfma_f32_16x16x32_bf16(wf, h, acc[dt], 0, 0, 0);
            }
        }
        // ---- sub-step 2 ----
        {
            short8 h = cvt8(pa2, pb2);
            int nk = ks + 5;
            const float* np = rp + (size_t)(nk < 24 ? nk : 0) * 32;
            pa2 = *reinterpret_cast<const float4*>(np);
            pb2 = *reinterpret_cast<const float4*>(np + 4);
            int k0 = (ks + 2) * 32 + lg * 8;
#pragma unroll
            for (int dt = 0; dt < 8; ++dt) {
                short8 wf = *reinterpret_cast<const short8*>(Wb + (size_t)(dt * 16 + l15) * HH + k0);
                acc[dt] = __builtin_amdgcn_mfma_f32_16x16x32_bf16(wf, h, acc[dt], 0, 0, 0);
            }
        }
    }

    // normalize per token + store bf16
    float ss = 0.f;
#pragma unroll
    for (int dt = 0; dt < 8; ++dt) {
        ss += acc[dt][0] * acc[dt][0];
        ss += acc[dt][1] * acc[dt][1];
        ss += acc[dt][2] * acc[dt][2];
        ss += acc[dt][3] * acc[dt][3];
    }
    ss += __shfl_xor(ss, 16, 64);
    ss += __shfl_xor(ss, 32, 64);
    int mk = mask[tok];
    float scale = mk ? (1.0f / fmaxf(sqrtf(ss), 1e-12f)) : 0.0f;
    unsigned short* orow = dst + (size_t)tok * DD + lg * 4;
#pragma unroll
    for (int dt = 0; dt < 8; ++dt) {
        ushort4 o;
        o.x = bf16r(acc[dt][0] * scale);
        o.y = bf16r(acc[dt][1] * scale);
        o.z = bf16r(acc[dt][2] * scale);
        o.w = bf16r(acc[dt][3] * scale);
        *reinterpret_cast<ushort4*>(orow + dt * 16) = o;
    }
}

// ---------------- kernel 3: sim + rowmax per 128-doc chunk ----------------
// grid (64 batches x 8 chunks); block 256 thr = 4 waves; LDS 64KB -> 2 blocks/CU.
__global__ __launch_bounds__(256) void k_sim(const unsigned short* __restrict__ qe,
                                             const unsigned short* __restrict__ de,
                                             float* __restrict__ partial) {
    __shared__ uint4 qs[SQL * 16];     // 32KB
    __shared__ uint4 dsm[SQL * 16];    // 32KB (128 doc rows)
    __shared__ float bm[4][SQL];

    int b = blockIdx.x >> 3;
    int c = blockIdx.x & 7;

    const uint4* qg = reinterpret_cast<const uint4*>(qe + (size_t)b * SQL * DD);
    for (int idx = threadIdx.x; idx < SQL * 16; idx += 256) {
        int row = idx >> 4, ch = idx & 15;
        qs[row * 16 + (ch ^ (row & 7))] = qg[idx];
    }
    const uint4* dg = reinterpret_cast<const uint4*>(de + ((size_t)b * SDL + (size_t)c * 128) * DD);
    for (int idx = threadIdx.x; idx < SQL * 16; idx += 256) {
        int row = idx >> 4, ch = idx & 15;
        dsm[row * 16 + (ch ^ (row & 7))] = dg[idx];
    }
    __syncthreads();

    int lane = threadIdx.x & 63;
    int w = threadIdx.x >> 6;
    int l15 = lane & 15;
    int lg = lane >> 4;

    float rmax[8][4];
#pragma unroll
    for (int i = 0; i < 8; ++i)
#pragma unroll
        for (int r = 0; r < 4; ++r) rmax[i][r] = -3.4e38f;

    for (int i = 0; i < 8; ++i) {
        short8 a[4];
        int arow = i * 16 + l15;
#pragma unroll
        for (int ks = 0; ks < 4; ++ks) {
            int ch = ks * 4 + lg;
            a[ks] = *reinterpret_cast<const short8*>(&qs[arow * 16 + (ch ^ (arow & 7))]);
        }
#pragma unroll
        for (int jj = 0; jj < 2; ++jj) {
            int drow = (w * 2 + jj) * 16 + l15;
            f32x4 accv = (f32x4){0.f, 0.f, 0.f, 0.f};
#pragma unroll
            for (int ks = 0; ks < 4; ++ks) {
                int ch = ks * 4 + lg;
                short8 bf = *reinterpret_cast<const short8*>(&dsm[drow * 16 + (ch ^ (drow & 7))]);
                accv = __builtin_amdgcn_mfma_f32_16x16x32_bf16(a[ks], bf, accv, 0, 0, 0);
            }
#pragma unroll
            for (int r = 0; r < 4; ++r) rmax[i][r] = fmaxf(rmax[i][r], accv[r]);
        }
    }

    // reduce max over the 16 doc-columns held across l15 lanes
#pragma unroll
    for (int i = 0; i < 8; ++i) {
#pragma unroll
        for (int r = 0; r < 4; ++r) {
            float v = rmax[i][r];
            v = fmaxf(v, __shfl_xor(v, 1, 64));
            v = fmaxf(v, __shfl_xor(v, 2, 64));
            v = fmaxf(v, __shfl_xor(v, 4, 64));
            v = fmaxf(v, __shfl_xor(v, 8, 64));
            if (l15 == 0) bm[w][i * 16 + lg * 4 + r] = v;
        }
    }
    __syncthreads();

    if (threadIdx.x < SQL) {
        int sq = threadIdx.x;
        float m = fmaxf(fmaxf(bm[0][sq], bm[1][sq]), fmaxf(bm[2][sq], bm[3][sq]));
        partial[((size_t)b * 8 + c) * SQL + sq] = m;
    }
}

// ---------------- kernel 4: max over 8 chunks, sum over sq ----------------
__global__ __launch_bounds__(128) void k_reduce(const float* __restrict__ partial,
                                                float* __restrict__ out) {
    int b = blockIdx.x;
    int sq = threadIdx.x;  // 128 threads
    const float* p = partial + (size_t)b * 8 * SQL;
    float m = -3.4e38f;
#pragma unroll
    for (int k = 0; k < 8; ++k) m = fmaxf(m, p[k * SQL + sq]);
    float s = m;
    s += __shfl_xor(s, 1, 64);
    s += __shfl_xor(s, 2, 64);
    s += __shfl_xor(s, 4, 64);
    s += __shfl_xor(s, 8, 64);
    s += __shfl_xor(s, 16, 64);
    s += __shfl_xor(s, 32, 64);
    __shared__ float tmp[2];
    int lane = threadIdx.x & 63;
    int wv = threadIdx.x >> 6;
    if (lane == 0) tmp[wv] = s;
    __syncthreads();
    if (threadIdx.x == 0) out[b] = tmp[0] + tmp[1];
}

extern "C" void kernel_launch(void* const* d_in, const int* in_sizes, int n_in,
                              void* d_out, int out_size, void* d_ws, size_t ws_size,
                              hipStream_t stream) {
    const float* qh = (const float*)d_in[0];
    const int* qm = (const int*)d_in[1];
    const float* dh = (const float*)d_in[2];
    const int* dm = (const int*)d_in[3];
    const float* W = (const float*)d_in[4];
    float* out = (float*)d_out;

    char* ws = (char*)d_ws;
    // layout: Wb [0,196608) | qe [196608, 2293760) | de [2293760, 19070976) | partial [19070976, 19333120)
    unsigned short* Wb = (unsigned short*)(ws);
    unsigned short* qe = (unsigned short*)(ws + 196608);
    unsigned short* de = (unsigned short*)(ws + 2293760);
    float* partial = (float*)(ws + 19070976);

    hipLaunchKernelGGL(k_wconv, dim3(96), dim3(256), 0, stream, W, Wb);
    hipLaunchKernelGGL(k_project, dim3(NB * 9 * 2), dim3(256), 0, stream,
                       qh, qm, dh, dm, Wb, qe, de);
    hipLaunchKernelGGL(k_sim, dim3(NB * 8), dim3(256), 0, stream, qe, de, partial);
    hipLaunchKernelGGL(k_reduce, dim3(NB), dim3(128), 0, stream, partial, out);
}

// Round 7
// 343.022 us; speedup vs baseline: 1.3591x; 1.3591x over previous
//
#include <hip/hip_runtime.h>
#include <hip/hip_bf16.h>

// ColBERT MaxSim: B=64, SQ=128, SD=1024, H=768, D=128
#define NB 64
#define SQL 128
#define SDL 1024
#define HH 768
#define DD 128

typedef __attribute__((ext_vector_type(8))) short short8;
typedef __attribute__((ext_vector_type(4))) float f32x4;

__device__ __forceinline__ unsigned short bf16r(float f) {
    unsigned int u = __builtin_bit_cast(unsigned int, f);
    u += 0x7FFFu + ((u >> 16) & 1u);
    return (unsigned short)(u >> 16);
}

__device__ __forceinline__ short8 cvt8(float4 a, float4 b) {
    short8 s;
    s[0] = (short)bf16r(a.x); s[1] = (short)bf16r(a.y);
    s[2] = (short)bf16r(a.z); s[3] = (short)bf16r(a.w);
    s[4] = (short)bf16r(b.x); s[5] = (short)bf16r(b.y);
    s[6] = (short)bf16r(b.z); s[7] = (short)bf16r(b.w);
    return s;
}

// ---------------- kernel 1: W fp32 -> bf16 (linear image; validated r2/r3) ---
__global__ __launch_bounds__(256) void k_wconv(const float* __restrict__ W,
                                               unsigned short* __restrict__ Wb) {
    int i = blockIdx.x * 256 + threadIdx.x;   // grid 96, one float4/thread
    float4 v = reinterpret_cast<const float4*>(W)[i];
    ushort4 o;
    o.x = bf16r(v.x); o.y = bf16r(v.y); o.z = bf16r(v.z); o.w = bf16r(v.w);
    reinterpret_cast<ushort4*>(Wb)[i] = o;
}

// ---------------- kernel 2: project + L2-normalize ----------------
// 128 tokens/block (32/wave). W staged per 64-k chunk (16KB) in LDS,
// double-buffered, REGISTER-staged (global->reg early, ds_write late; T14).
// LDS image XOR-swizzled on 16B granules: slot gp holds source granule
// gp ^ (row&7); reads apply the same XOR. h rows: depth-1 reg prefetch.
__global__ __launch_bounds__(256, 3) void k_project(
        const float* __restrict__ qh, const int* __restrict__ qm,
        const float* __restrict__ dh, const int* __restrict__ dm,
        const unsigned short* __restrict__ Wb,
        unsigned short* __restrict__ qe, unsigned short* __restrict__ de) {
    __shared__ unsigned short w_lds[2][8192];   // 2 x 16KB

    int bx = blockIdx.x;          // 576 = 64 b * 9 segs
    int b = bx / 9;
    int seg = bx % 9;
    const float* src;
    const int* mask;
    unsigned short* dst;
    if (seg == 0) {
        src = qh + (size_t)b * SQL * HH;
        mask = qm + (size_t)b * SQL;
        dst = qe + (size_t)b * SQL * DD;
    } else {
        size_t off = (size_t)(seg - 1) * 128;
        src = dh + ((size_t)b * SDL + off) * HH;
        mask = dm + (size_t)b * SDL + off;
        dst = de + ((size_t)b * SDL + off) * DD;
    }

    int tid = threadIdx.x;
    int lane = tid & 63;
    int w = tid >> 6;
    int l15 = lane & 15;
    int lg = lane >> 4;

    // per-thread staging geometry (c-independent): 4 granules of 16B each
    int g0 = tid,        r0 = g0 >> 3, p0 = g0 & 7, s0i = p0 ^ (r0 & 7);
    int g1 = tid + 256,  r1 = g1 >> 3, p1 = g1 & 7, s1i = p1 ^ (r1 & 7);
    int g2 = tid + 512,  r2 = g2 >> 3, p2 = g2 & 7, s2i = p2 ^ (r2 & 7);
    int g3 = tid + 768,  r3 = g3 >> 3, p3 = g3 & 7, s3i = p3 ^ (r3 & 7);
    const unsigned short* wg0 = Wb + (size_t)r0 * HH + s0i * 8;
    const unsigned short* wg1 = Wb + (size_t)r1 * HH + s1i * 8;
    const unsigned short* wg2 = Wb + (size_t)r2 * HH + s2i * 8;
    const unsigned short* wg3 = Wb + (size_t)r3 * HH + s3i * 8;
    int lo0 = r0 * 64 + p0 * 8;
    int lo1 = r1 * 64 + p1 * 8;
    int lo2 = r2 * 64 + p2 * 8;
    int lo3 = r3 * 64 + p3 * 8;

    const float* rp0 = src + (size_t)(w * 32 + l15) * HH + lg * 8;
    const float* rp1 = src + (size_t)(w * 32 + 16 + l15) * HH + lg * 8;

    f32x4 acc[8][2];
#pragma unroll
    for (int dt = 0; dt < 8; ++dt) {
        acc[dt][0] = (f32x4){0.f, 0.f, 0.f, 0.f};
        acc[dt][1] = (f32x4){0.f, 0.f, 0.f, 0.f};
    }

    // prologue: stage chunk 0 into buf 0; prefetch h k-step 0
    {
        short8 t0 = *reinterpret_cast<const short8*>(wg0);
        short8 t1 = *reinterpret_cast<const short8*>(wg1);
        short8 t2 = *reinterpret_cast<const short8*>(wg2);
        short8 t3 = *reinterpret_cast<const short8*>(wg3);
        *reinterpret_cast<short8*>(&w_lds[0][lo0]) = t0;
        *reinterpret_cast<short8*>(&w_lds[0][lo1]) = t1;
        *reinterpret_cast<short8*>(&w_lds[0][lo2]) = t2;
        *reinterpret_cast<short8*>(&w_lds[0][lo3]) = t3;
    }
    float4 pa0 = *reinterpret_cast<const float4*>(rp0);
    float4 pb0 = *reinterpret_cast<const float4*>(rp0 + 4);
    float4 pa1 = *reinterpret_cast<const float4*>(rp1);
    float4 pb1 = *reinterpret_cast<const float4*>(rp1 + 4);
    __syncthreads();

    int buf = 0;
    for (int c = 0; c < 12; ++c) {
        // issue next-chunk W loads early (latency hides under compute)
        short8 st0, st1, st2, st3;
        if (c < 11) {
            int ko = (c + 1) * 64;
            st0 = *reinterpret_cast<const short8*>(wg0 + ko);
            st1 = *reinterpret_cast<const short8*>(wg1 + ko);
            st2 = *reinterpret_cast<const short8*>(wg2 + ko);
            st3 = *reinterpret_cast<const short8*>(wg3 + ko);
        }
        // ---- k-step ks2 = 0 (global kk = 2c) ----
        {
            short8 h0 = cvt8(pa0, pb0);
            short8 h1 = cvt8(pa1, pb1);
            int kk = c * 2;
            const float* q0 = rp0 + (size_t)(kk + 1) * 32;
            const float* q1 = rp1 + (size_t)(kk + 1) * 32;
            pa0 = *reinterpret_cast<const float4*>(q0);
            pb0 = *reinterpret_cast<const float4*>(q0 + 4);
            pa1 = *reinterpret_cast<const float4*>(q1);
            pb1 = *reinterpret_cast<const float4*>(q1 + 4);
#pragma unroll
            for (int dt = 0; dt < 8; ++dt) {
                int row = dt * 16 + l15;
                int gp = lg ^ (l15 & 7);
                short8 wf = *reinterpret_cast<const short8*>(&w_lds[buf][row * 64 + gp * 8]);
                acc[dt][0] = __builtin_amdgcn_mfma_f32_16x16x32_bf16(wf, h0, acc[dt][0], 0, 0, 0);
                acc[dt][1] = __builtin_amdgcn_mfma_f32_16x16x32_bf16(wf, h1, acc[dt][1], 0, 0, 0);
            }
        }
        // ---- k-step ks2 = 1 (global kk = 2c+1) ----
        {
            short8 h0 = cvt8(pa0, pb0);
            short8 h1 = cvt8(pa1, pb1);
            int kk = c * 2 + 1;
            int nk = (kk + 1 < 24) ? (kk + 1) : 0;   // tail: harmless reload
            const float* q0 = rp0 + (size_t)nk * 32;
            const float* q1 = rp1 + (size_t)nk * 32;
            pa0 = *reinterpret_cast<const float4*>(q0);
            pb0 = *reinterpret_cast<const float4*>(q0 + 4);
            pa1 = *reinterpret_cast<const float4*>(q1);
            pb1 = *reinterpret_cast<const float4*>(q1 + 4);
#pragma unroll
            for (int dt = 0; dt < 8; ++dt) {
                int row = dt * 16 + l15;
                int gp = (4 + lg) ^ (l15 & 7);
                short8 wf = *reinterpret_cast<const short8*>(&w_lds[buf][row * 64 + gp * 8]);
                acc[dt][0] = __builtin_amdgcn_mfma_f32_16x16x32_bf16(wf, h0, acc[dt][0], 0, 0, 0);
                acc[dt][1] = __builtin_amdgcn_mfma_f32_16x16x32_bf16(wf, h1, acc[dt][1], 0, 0, 0);
            }
        }
        // write next chunk to the other buffer (nobody reads it this iter)
        if (c < 11) {
            *reinterpret_cast<short8*>(&w_lds[buf ^ 1][lo0]) = st0;
            *reinterpret_cast<short8*>(&w_lds[buf ^ 1][lo1]) = st1;
            *reinterpret_cast<short8*>(&w_lds[buf ^ 1][lo2]) = st2;
            *reinterpret_cast<short8*>(&w_lds[buf ^ 1][lo3]) = st3;
        }
        __syncthreads();
        buf ^= 1;
    }

    // normalize per token + store bf16 (validated r2/r3 epilogue)
#pragma unroll
    for (int jt = 0; jt < 2; ++jt) {
        float ss = 0.f;
#pragma unroll
        for (int dt = 0; dt < 8; ++dt) {
            ss += acc[dt][jt][0] * acc[dt][jt][0];
            ss += acc[dt][jt][1] * acc[dt][jt][1];
            ss += acc[dt][jt][2] * acc[dt][jt][2];
            ss += acc[dt][jt][3] * acc[dt][jt][3];
        }
        ss += __shfl_xor(ss, 16, 64);
        ss += __shfl_xor(ss, 32, 64);
        int tokl = w * 32 + jt * 16 + l15;
        int mk = mask[tokl];
        float scale = mk ? (1.0f / fmaxf(sqrtf(ss), 1e-12f)) : 0.0f;
        unsigned short* orow = dst + (size_t)tokl * DD + lg * 4;
#pragma unroll
        for (int dt = 0; dt < 8; ++dt) {
            ushort4 o;
            o.x = bf16r(acc[dt][jt][0] * scale);
            o.y = bf16r(acc[dt][jt][1] * scale);
            o.z = bf16r(acc[dt][jt][2] * scale);
            o.w = bf16r(acc[dt][jt][3] * scale);
            *reinterpret_cast<ushort4*>(orow + dt * 16) = o;
        }
    }
}

// ---------------- kernel 3: sim + rowmax per 128-doc chunk (validated r3) ----
__global__ __launch_bounds__(256) void k_sim(const unsigned short* __restrict__ qe,
                                             const unsigned short* __restrict__ de,
                                             float* __restrict__ partial) {
    __shared__ uint4 qs[SQL * 16];     // 32KB
    __shared__ uint4 dsm[SQL * 16];    // 32KB (128 doc rows)
    __shared__ float bm[4][SQL];

    int b = blockIdx.x >> 3;
    int c = blockIdx.x & 7;

    const uint4* qg = reinterpret_cast<const uint4*>(qe + (size_t)b * SQL * DD);
    for (int idx = threadIdx.x; idx < SQL * 16; idx += 256) {
        int row = idx >> 4, ch = idx & 15;
        qs[row * 16 + (ch ^ (row & 7))] = qg[idx];
    }
    const uint4* dg = reinterpret_cast<const uint4*>(de + ((size_t)b * SDL + (size_t)c * 128) * DD);
    for (int idx = threadIdx.x; idx < SQL * 16; idx += 256) {
        int row = idx >> 4, ch = idx & 15;
        dsm[row * 16 + (ch ^ (row & 7))] = dg[idx];
    }
    __syncthreads();

    int lane = threadIdx.x & 63;
    int w = threadIdx.x >> 6;
    int l15 = lane & 15;
    int lg = lane >> 4;

    float rmax[8][4];
#pragma unroll
    for (int i = 0; i < 8; ++i)
#pragma unroll
        for (int r = 0; r < 4; ++r) rmax[i][r] = -3.4e38f;

    for (int i = 0; i < 8; ++i) {
        short8 a[4];
        int arow = i * 16 + l15;
#pragma unroll
        for (int ks = 0; ks < 4; ++ks) {
            int ch = ks * 4 + lg;
            a[ks] = *reinterpret_cast<const short8*>(&qs[arow * 16 + (ch ^ (arow & 7))]);
        }
#pragma unroll
        for (int jj = 0; jj < 2; ++jj) {
            int drow = (w * 2 + jj) * 16 + l15;
            f32x4 accv = (f32x4){0.f, 0.f, 0.f, 0.f};
#pragma unroll
            for (int ks = 0; ks < 4; ++ks) {
                int ch = ks * 4 + lg;
                short8 bf = *reinterpret_cast<const short8*>(&dsm[drow * 16 + (ch ^ (drow & 7))]);
                accv = __builtin_amdgcn_mfma_f32_16x16x32_bf16(a[ks], bf, accv, 0, 0, 0);
            }
#pragma unroll
            for (int r = 0; r < 4; ++r) rmax[i][r] = fmaxf(rmax[i][r], accv[r]);
        }
    }

#pragma unroll
    for (int i = 0; i < 8; ++i) {
#pragma unroll
        for (int r = 0; r < 4; ++r) {
            float v = rmax[i][r];
            v = fmaxf(v, __shfl_xor(v, 1, 64));
            v = fmaxf(v, __shfl_xor(v, 2, 64));
            v = fmaxf(v, __shfl_xor(v, 4, 64));
            v = fmaxf(v, __shfl_xor(v, 8, 64));
            if (l15 == 0) bm[w][i * 16 + lg * 4 + r] = v;
        }
    }
    __syncthreads();

    if (threadIdx.x < SQL) {
        int sq = threadIdx.x;
        float m = fmaxf(fmaxf(bm[0][sq], bm[1][sq]), fmaxf(bm[2][sq], bm[3][sq]));
        partial[((size_t)b * 8 + c) * SQL + sq] = m;
    }
}

// ---------------- kernel 4: max over 8 chunks, sum over sq (validated r3) ----
__global__ __launch_bounds__(128) void k_reduce(const float* __restrict__ partial,
                                                float* __restrict__ out) {
    int b = blockIdx.x;
    int sq = threadIdx.x;  // 128 threads
    const float* p = partial + (size_t)b * 8 * SQL;
    float m = -3.4e38f;
#pragma unroll
    for (int k = 0; k < 8; ++k) m = fmaxf(m, p[k * SQL + sq]);
    float s = m;
    s += __shfl_xor(s, 1, 64);
    s += __shfl_xor(s, 2, 64);
    s += __shfl_xor(s, 4, 64);
    s += __shfl_xor(s, 8, 64);
    s += __shfl_xor(s, 16, 64);
    s += __shfl_xor(s, 32, 64);
    __shared__ float tmp[2];
    int lane = threadIdx.x & 63;
    int wv = threadIdx.x >> 6;
    if (lane == 0) tmp[wv] = s;
    __syncthreads();
    if (threadIdx.x == 0) out[b] = tmp[0] + tmp[1];
}

extern "C" void kernel_launch(void* const* d_in, const int* in_sizes, int n_in,
                              void* d_out, int out_size, void* d_ws, size_t ws_size,
                              hipStream_t stream) {
    const float* qh = (const float*)d_in[0];
    const int* qm = (const int*)d_in[1];
    const float* dh = (const float*)d_in[2];
    const int* dm = (const int*)d_in[3];
    const float* W = (const float*)d_in[4];
    float* out = (float*)d_out;

    char* ws = (char*)d_ws;
    // layout: Wb [0,196608) | qe [196608, 2293760) | de [2293760, 19070976) | partial [19070976, 19333120)
    unsigned short* Wb = (unsigned short*)(ws);
    unsigned short* qe = (unsigned short*)(ws + 196608);
    unsigned short* de = (unsigned short*)(ws + 2293760);
    float* partial = (float*)(ws + 19070976);

    hipLaunchKernelGGL(k_wconv, dim3(96), dim3(256), 0, stream, W, Wb);
    hipLaunchKernelGGL(k_project, dim3(NB * 9), dim3(256), 0, stream,
                       qh, qm, dh, dm, Wb, qe, de);
    hipLaunchKernelGGL(k_sim, dim3(NB * 8), dim3(256), 0, stream, qe, de, partial);
    hipLaunchKernelGGL(k_reduce, dim3(NB), dim3(128), 0, stream, partial, out);
}

// Round 8
// 334.937 us; speedup vs baseline: 1.3919x; 1.0241x over previous
//
#include <hip/hip_runtime.h>
#include <hip/hip_bf16.h>

// ColBERT MaxSim: B=64, SQ=128, SD=1024, H=768, D=128
#define NB 64
#define SQL 128
#define SDL 1024
#define HH 768
#define DD 128

typedef __attribute__((ext_vector_type(8))) short short8;
typedef __attribute__((ext_vector_type(4))) float f32x4;

__device__ __forceinline__ unsigned short bf16r(float f) {
    unsigned int u = __builtin_bit_cast(unsigned int, f);
    u += 0x7FFFu + ((u >> 16) & 1u);
    return (unsigned short)(u >> 16);
}

__device__ __forceinline__ short8 cvt8(float4 a, float4 b) {
    short8 s;
    s[0] = (short)bf16r(a.x); s[1] = (short)bf16r(a.y);
    s[2] = (short)bf16r(a.z); s[3] = (short)bf16r(a.w);
    s[4] = (short)bf16r(b.x); s[5] = (short)bf16r(b.y);
    s[6] = (short)bf16r(b.z); s[7] = (short)bf16r(b.w);
    return s;
}

// ---------------- kernel 1: W fp32 -> bf16 (linear image; validated) ---------
__global__ __launch_bounds__(256) void k_wconv(const float* __restrict__ W,
                                               unsigned short* __restrict__ Wb) {
    int i = blockIdx.x * 256 + threadIdx.x;   // grid 96, one float4/thread
    float4 v = reinterpret_cast<const float4*>(W)[i];
    ushort4 o;
    o.x = bf16r(v.x); o.y = bf16r(v.y); o.z = bf16r(v.z); o.w = bf16r(v.w);
    reinterpret_cast<ushort4*>(Wb)[i] = o;
}

// ---------------- kernel 2: project + L2-normalize ----------------
// 128 tokens/block (32/wave). W staged per 128-k chunk (32KB) in LDS,
// double-buffered (64KB, 2 blocks/CU), register-staged early-load/late-write.
// Swizzle: position p of row r holds source granule p^(r&15); read applies
// the same XOR. h rows: depth-4 named-register prefetch (16 float4 in
// flight/thread) to cover HBM latency; 6 barriers/block total.
__global__ __launch_bounds__(256, 2) void k_project(
        const float* __restrict__ qh, const int* __restrict__ qm,
        const float* __restrict__ dh, const int* __restrict__ dm,
        const unsigned short* __restrict__ Wb,
        unsigned short* __restrict__ qe, unsigned short* __restrict__ de) {
    __shared__ unsigned short w_lds[2][16384];   // 2 x 32KB

    int bx = blockIdx.x;          // 576 = 64 b * 9 segs
    int b = bx / 9;
    int seg = bx % 9;
    const float* src;
    const int* mask;
    unsigned short* dst;
    if (seg == 0) {
        src = qh + (size_t)b * SQL * HH;
        mask = qm + (size_t)b * SQL;
        dst = qe + (size_t)b * SQL * DD;
    } else {
        size_t off = (size_t)(seg - 1) * 128;
        src = dh + ((size_t)b * SDL + off) * HH;
        mask = dm + (size_t)b * SDL + off;
        dst = de + ((size_t)b * SDL + off) * DD;
    }

    int tid = threadIdx.x;
    int lane = tid & 63;
    int w = tid >> 6;
    int l15 = lane & 15;
    int lg = lane >> 4;

    // --- W staging geometry: 8 granules(16B)/thread, rows row0+j*16 ---
    int row0 = tid >> 4;            // 0..15
    int pos  = tid & 15;            // position within row (16 granules/row)
    int sg   = pos ^ row0;          // source granule (swizzle involution)
    const unsigned short* wsrc = Wb + (size_t)row0 * HH + sg * 8;
    int ldsoff = row0 * 128 + pos * 8;      // shorts; row stride 128 shorts

    const float* rp0 = src + (size_t)(w * 32 + l15) * HH + lg * 8;
    const float* rp1 = src + (size_t)(w * 32 + 16 + l15) * HH + lg * 8;

    f32x4 acc[8][2];
#pragma unroll
    for (int dt = 0; dt < 8; ++dt) {
        acc[dt][0] = (f32x4){0.f, 0.f, 0.f, 0.f};
        acc[dt][1] = (f32x4){0.f, 0.f, 0.f, 0.f};
    }

    // prologue: stage chunk 0 into buf 0
#pragma unroll
    for (int j = 0; j < 8; ++j) {
        short8 t = *reinterpret_cast<const short8*>(wsrc + (size_t)j * 16 * HH);
        *reinterpret_cast<short8*>(&w_lds[0][ldsoff + j * 2048]) = t;
    }
    // prefetch h k-steps 0..3 into sets A..D (each: 2 rows x 2 float4)
    float4 a0A = *reinterpret_cast<const float4*>(rp0);
    float4 b0A = *reinterpret_cast<const float4*>(rp0 + 4);
    float4 a1A = *reinterpret_cast<const float4*>(rp1);
    float4 b1A = *reinterpret_cast<const float4*>(rp1 + 4);
    float4 a0B = *reinterpret_cast<const float4*>(rp0 + 32);
    float4 b0B = *reinterpret_cast<const float4*>(rp0 + 36);
    float4 a1B = *reinterpret_cast<const float4*>(rp1 + 32);
    float4 b1B = *reinterpret_cast<const float4*>(rp1 + 36);
    float4 a0C = *reinterpret_cast<const float4*>(rp0 + 64);
    float4 b0C = *reinterpret_cast<const float4*>(rp0 + 68);
    float4 a1C = *reinterpret_cast<const float4*>(rp1 + 64);
    float4 b1C = *reinterpret_cast<const float4*>(rp1 + 68);
    float4 a0D = *reinterpret_cast<const float4*>(rp0 + 96);
    float4 b0D = *reinterpret_cast<const float4*>(rp0 + 100);
    float4 a1D = *reinterpret_cast<const float4*>(rp1 + 96);
    float4 b1D = *reinterpret_cast<const float4*>(rp1 + 100);
    __syncthreads();

    // one k-step: consume one set, refill it for k-step NEXTKK, 16 MFMA
#define KSTEP(A0_, B0_, A1_, B1_, KSIDX, NEXTKK)                               \
    {                                                                          \
        short8 h0 = cvt8(A0_, B0_);                                            \
        short8 h1 = cvt8(A1_, B1_);                                            \
        int nk = (NEXTKK) < 24 ? (NEXTKK) : 0;                                 \
        const float* q0 = rp0 + (size_t)nk * 32;                               \
        const float* q1 = rp1 + (size_t)nk * 32;                               \
        A0_ = *reinterpret_cast<const float4*>(q0);                            \
        B0_ = *reinterpret_cast<const float4*>(q0 + 4);                        \
        A1_ = *reinterpret_cast<const float4*>(q1);                            \
        B1_ = *reinterpret_cast<const float4*>(q1 + 4);                        \
        _Pragma("unroll")                                                      \
        for (int dt = 0; dt < 8; ++dt) {                                       \
            int p = ((KSIDX) * 4 + lg) ^ l15;                                  \
            short8 wf = *reinterpret_cast<const short8*>(                      \
                &w_lds[buf][(dt * 16 + l15) * 128 + p * 8]);                   \
            acc[dt][0] = __builtin_amdgcn_mfma_f32_16x16x32_bf16(wf, h0, acc[dt][0], 0, 0, 0); \
            acc[dt][1] = __builtin_amdgcn_mfma_f32_16x16x32_bf16(wf, h1, acc[dt][1], 0, 0, 0); \
        }                                                                      \
    }

    int buf = 0;
    for (int c = 0; c < 6; ++c) {
        // issue next-chunk W loads early (whole chunk of compute to cover them)
        short8 st[8];
        if (c < 5) {
            int ko = (c + 1) * 128;   // shorts into the row
#pragma unroll
            for (int j = 0; j < 8; ++j)
                st[j] = *reinterpret_cast<const short8*>(wsrc + (size_t)j * 16 * HH + ko);
        }
        KSTEP(a0A, b0A, a1A, b1A, 0, 4 * c + 4)
        KSTEP(a0B, b0B, a1B, b1B, 1, 4 * c + 5)
        KSTEP(a0C, b0C, a1C, b1C, 2, 4 * c + 6)
        KSTEP(a0D, b0D, a1D, b1D, 3, 4 * c + 7)
        if (c < 5) {
#pragma unroll
            for (int j = 0; j < 8; ++j)
                *reinterpret_cast<short8*>(&w_lds[buf ^ 1][ldsoff + j * 2048]) = st[j];
        }
        __syncthreads();
        buf ^= 1;
    }
#undef KSTEP

    // normalize per token + store bf16 (validated epilogue)
#pragma unroll
    for (int jt = 0; jt < 2; ++jt) {
        float ss = 0.f;
#pragma unroll
        for (int dt = 0; dt < 8; ++dt) {
            ss += acc[dt][jt][0] * acc[dt][jt][0];
            ss += acc[dt][jt][1] * acc[dt][jt][1];
            ss += acc[dt][jt][2] * acc[dt][jt][2];
            ss += acc[dt][jt][3] * acc[dt][jt][3];
        }
        ss += __shfl_xor(ss, 16, 64);
        ss += __shfl_xor(ss, 32, 64);
        int tokl = w * 32 + jt * 16 + l15;
        int mk = mask[tokl];
        float scale = mk ? (1.0f / fmaxf(sqrtf(ss), 1e-12f)) : 0.0f;
        unsigned short* orow = dst + (size_t)tokl * DD + lg * 4;
#pragma unroll
        for (int dt = 0; dt < 8; ++dt) {
            ushort4 o;
            o.x = bf16r(acc[dt][jt][0] * scale);
            o.y = bf16r(acc[dt][jt][1] * scale);
            o.z = bf16r(acc[dt][jt][2] * scale);
            o.w = bf16r(acc[dt][jt][3] * scale);
            *reinterpret_cast<ushort4*>(orow + dt * 16) = o;
        }
    }
}

// ---------------- kernel 3: sim + rowmax per 128-doc chunk (validated) -------
__global__ __launch_bounds__(256) void k_sim(const unsigned short* __restrict__ qe,
                                             const unsigned short* __restrict__ de,
                                             float* __restrict__ partial) {
    __shared__ uint4 qs[SQL * 16];     // 32KB
    __shared__ uint4 dsm[SQL * 16];    // 32KB (128 doc rows)
    __shared__ float bm[4][SQL];

    int b = blockIdx.x >> 3;
    int c = blockIdx.x & 7;

    const uint4* qg = reinterpret_cast<const uint4*>(qe + (size_t)b * SQL * DD);
    for (int idx = threadIdx.x; idx < SQL * 16; idx += 256) {
        int row = idx >> 4, ch = idx & 15;
        qs[row * 16 + (ch ^ (row & 7))] = qg[idx];
    }
    const uint4* dg = reinterpret_cast<const uint4*>(de + ((size_t)b * SDL + (size_t)c * 128) * DD);
    for (int idx = threadIdx.x; idx < SQL * 16; idx += 256) {
        int row = idx >> 4, ch = idx & 15;
        dsm[row * 16 + (ch ^ (row & 7))] = dg[idx];
    }
    __syncthreads();

    int lane = threadIdx.x & 63;
    int w = threadIdx.x >> 6;
    int l15 = lane & 15;
    int lg = lane >> 4;

    float rmax[8][4];
#pragma unroll
    for (int i = 0; i < 8; ++i)
#pragma unroll
        for (int r = 0; r < 4; ++r) rmax[i][r] = -3.4e38f;

    for (int i = 0; i < 8; ++i) {
        short8 a[4];
        int arow = i * 16 + l15;
#pragma unroll
        for (int ks = 0; ks < 4; ++ks) {
            int ch = ks * 4 + lg;
            a[ks] = *reinterpret_cast<const short8*>(&qs[arow * 16 + (ch ^ (arow & 7))]);
        }
#pragma unroll
        for (int jj = 0; jj < 2; ++jj) {
            int drow = (w * 2 + jj) * 16 + l15;
            f32x4 accv = (f32x4){0.f, 0.f, 0.f, 0.f};
#pragma unroll
            for (int ks = 0; ks < 4; ++ks) {
                int ch = ks * 4 + lg;
                short8 bf = *reinterpret_cast<const short8*>(&dsm[drow * 16 + (ch ^ (drow & 7))]);
                accv = __builtin_amdgcn_mfma_f32_16x16x32_bf16(a[ks], bf, accv, 0, 0, 0);
            }
#pragma unroll
            for (int r = 0; r < 4; ++r) rmax[i][r] = fmaxf(rmax[i][r], accv[r]);
        }
    }

#pragma unroll
    for (int i = 0; i < 8; ++i) {
#pragma unroll
        for (int r = 0; r < 4; ++r) {
            float v = rmax[i][r];
            v = fmaxf(v, __shfl_xor(v, 1, 64));
            v = fmaxf(v, __shfl_xor(v, 2, 64));
            v = fmaxf(v, __shfl_xor(v, 4, 64));
            v = fmaxf(v, __shfl_xor(v, 8, 64));
            if (l15 == 0) bm[w][i * 16 + lg * 4 + r] = v;
        }
    }
    __syncthreads();

    if (threadIdx.x < SQL) {
        int sq = threadIdx.x;
        float m = fmaxf(fmaxf(bm[0][sq], bm[1][sq]), fmaxf(bm[2][sq], bm[3][sq]));
        partial[((size_t)b * 8 + c) * SQL + sq] = m;
    }
}

// ---------------- kernel 4: max over 8 chunks, sum over sq (validated) -------
__global__ __launch_bounds__(128) void k_reduce(const float* __restrict__ partial,
                                                float* __restrict__ out) {
    int b = blockIdx.x;
    int sq = threadIdx.x;  // 128 threads
    const float* p = partial + (size_t)b * 8 * SQL;
    float m = -3.4e38f;
#pragma unroll
    for (int k = 0; k < 8; ++k) m = fmaxf(m, p[k * SQL + sq]);
    float s = m;
    s += __shfl_xor(s, 1, 64);
    s += __shfl_xor(s, 2, 64);
    s += __shfl_xor(s, 4, 64);
    s += __shfl_xor(s, 8, 64);
    s += __shfl_xor(s, 16, 64);
    s += __shfl_xor(s, 32, 64);
    __shared__ float tmp[2];
    int lane = threadIdx.x & 63;
    int wv = threadIdx.x >> 6;
    if (lane == 0) tmp[wv] = s;
    __syncthreads();
    if (threadIdx.x == 0) out[b] = tmp[0] + tmp[1];
}

extern "C" void kernel_launch(void* const* d_in, const int* in_sizes, int n_in,
                              void* d_out, int out_size, void* d_ws, size_t ws_size,
                              hipStream_t stream) {
    const float* qh = (const float*)d_in[0];
    const int* qm = (const int*)d_in[1];
    const float* dh = (const float*)d_in[2];
    const int* dm = (const int*)d_in[3];
    const float* W = (const float*)d_in[4];
    float* out = (float*)d_out;

    char* ws = (char*)d_ws;
    // layout: Wb [0,196608) | qe [196608, 2293760) | de [2293760, 19070976) | partial [19070976, 19333120)
    unsigned short* Wb = (unsigned short*)(ws);
    unsigned short* qe = (unsigned short*)(ws + 196608);
    unsigned short* de = (unsigned short*)(ws + 2293760);
    float* partial = (float*)(ws + 19070976);

    hipLaunchKernelGGL(k_wconv, dim3(96), dim3(256), 0, stream, W, Wb);
    hipLaunchKernelGGL(k_project, dim3(NB * 9), dim3(256), 0, stream,
                       qh, qm, dh, dm, Wb, qe, de);
    hipLaunchKernelGGL(k_sim, dim3(NB * 8), dim3(256), 0, stream, qe, de, partial);
    hipLaunchKernelGGL(k_reduce, dim3(NB), dim3(128), 0, stream, partial, out);
}

// Round 9
// 328.700 us; speedup vs baseline: 1.4183x; 1.0190x over previous
//
#include <hip/hip_runtime.h>
#include <hip/hip_bf16.h>

// ColBERT MaxSim: B=64, SQ=128, SD=1024, H=768, D=128
#define NB 64
#define SQL 128
#define SDL 1024
#define HH 768
#define DD 128

typedef __attribute__((ext_vector_type(8))) short short8;
typedef __attribute__((ext_vector_type(4))) float f32x4;

__device__ __forceinline__ unsigned short bf16r(float f) {
    unsigned int u = __builtin_bit_cast(unsigned int, f);
    u += 0x7FFFu + ((u >> 16) & 1u);
    return (unsigned short)(u >> 16);
}

__device__ __forceinline__ short8 cvt8(float4 a, float4 b) {
    short8 s;
    s[0] = (short)bf16r(a.x); s[1] = (short)bf16r(a.y);
    s[2] = (short)bf16r(a.z); s[3] = (short)bf16r(a.w);
    s[4] = (short)bf16r(b.x); s[5] = (short)bf16r(b.y);
    s[6] = (short)bf16r(b.z); s[7] = (short)bf16r(b.w);
    return s;
}

// ---------------- kernel 1: W fp32 -> bf16 (linear image; validated) ---------
__global__ __launch_bounds__(256) void k_wconv(const float* __restrict__ W,
                                               unsigned short* __restrict__ Wb) {
    int i = blockIdx.x * 256 + threadIdx.x;   // grid 96, one float4/thread
    float4 v = reinterpret_cast<const float4*>(W)[i];
    ushort4 o;
    o.x = bf16r(v.x); o.y = bf16r(v.y); o.z = bf16r(v.z); o.w = bf16r(v.w);
    reinterpret_cast<ushort4*>(Wb)[i] = o;
}

// ---------------- kernel 2: project + L2-normalize ----------------
// 64 tokens/block, 16/wave (1 row per l15 lane) -> 1152 blocks = 4608 waves
// (4.5 waves/SIMD machine-wide; wave-starvation was r7/r8's limiter).
// W staged per 64-k chunk (16KB) in LDS, double-buffered (32KB), register-
// staged early-load/late-write; swizzle identical to r5/r7-validated version.
// h rows: depth-3 named-register prefetch.
__global__ __launch_bounds__(256, 4) void k_project(
        const float* __restrict__ qh, const int* __restrict__ qm,
        const float* __restrict__ dh, const int* __restrict__ dm,
        const unsigned short* __restrict__ Wb,
        unsigned short* __restrict__ qe, unsigned short* __restrict__ de) {
    __shared__ unsigned short w_lds[2][8192];   // 2 x 16KB

    int bx = blockIdx.x;          // 1152 = 64 b * 18 segs of 64 tokens
    int b = bx / 18;
    int s = bx % 18;
    const float* src;
    const int* mask;
    unsigned short* dst;
    if (s < 2) {
        size_t off = (size_t)s * 64;
        src = qh + ((size_t)b * SQL + off) * HH;
        mask = qm + (size_t)b * SQL + off;
        dst = qe + ((size_t)b * SQL + off) * DD;
    } else {
        size_t off = (size_t)(s - 2) * 64;
        src = dh + ((size_t)b * SDL + off) * HH;
        mask = dm + (size_t)b * SDL + off;
        dst = de + ((size_t)b * SDL + off) * DD;
    }

    int tid = threadIdx.x;
    int lane = tid & 63;
    int w = tid >> 6;
    int l15 = lane & 15;
    int lg = lane >> 4;

    // --- W staging geometry (r5/r7-validated): 4 granules(16B)/thread ---
    int g0 = tid,        r0 = g0 >> 3, p0 = g0 & 7, s0i = p0 ^ (r0 & 7);
    int g1 = tid + 256,  r1 = g1 >> 3, p1 = g1 & 7, s1i = p1 ^ (r1 & 7);
    int g2 = tid + 512,  r2 = g2 >> 3, p2 = g2 & 7, s2i = p2 ^ (r2 & 7);
    int g3 = tid + 768,  r3 = g3 >> 3, p3 = g3 & 7, s3i = p3 ^ (r3 & 7);
    const unsigned short* wg0 = Wb + (size_t)r0 * HH + s0i * 8;
    const unsigned short* wg1 = Wb + (size_t)r1 * HH + s1i * 8;
    const unsigned short* wg2 = Wb + (size_t)r2 * HH + s2i * 8;
    const unsigned short* wg3 = Wb + (size_t)r3 * HH + s3i * 8;
    int lo0 = r0 * 64 + p0 * 8;
    int lo1 = r1 * 64 + p1 * 8;
    int lo2 = r2 * 64 + p2 * 8;
    int lo3 = r3 * 64 + p3 * 8;

    // h: one token row per lane
    const float* rp = src + (size_t)(w * 16 + l15) * HH + lg * 8;

    f32x4 acc[8];
#pragma unroll
    for (int dt = 0; dt < 8; ++dt) acc[dt] = (f32x4){0.f, 0.f, 0.f, 0.f};

    // prologue: stage chunk 0 into buf 0; prefetch h k-steps 0..2 (sets A,B,C)
    {
        short8 t0 = *reinterpret_cast<const short8*>(wg0);
        short8 t1 = *reinterpret_cast<const short8*>(wg1);
        short8 t2 = *reinterpret_cast<const short8*>(wg2);
        short8 t3 = *reinterpret_cast<const short8*>(wg3);
        *reinterpret_cast<short8*>(&w_lds[0][lo0]) = t0;
        *reinterpret_cast<short8*>(&w_lds[0][lo1]) = t1;
        *reinterpret_cast<short8*>(&w_lds[0][lo2]) = t2;
        *reinterpret_cast<short8*>(&w_lds[0][lo3]) = t3;
    }
    float4 aA = *reinterpret_cast<const float4*>(rp);
    float4 bA = *reinterpret_cast<const float4*>(rp + 4);
    float4 aB = *reinterpret_cast<const float4*>(rp + 32);
    float4 bB = *reinterpret_cast<const float4*>(rp + 36);
    float4 aC = *reinterpret_cast<const float4*>(rp + 64);
    float4 bC = *reinterpret_cast<const float4*>(rp + 68);
    __syncthreads();

    int buf = 0;

    // consume one set for k-step KK, refill it for KK+3; 8 MFMA
#define KSTEP(A_, B_, KK)                                                      \
    {                                                                          \
        short8 h = cvt8(A_, B_);                                               \
        int nk = (KK) + 3 < 24 ? (KK) + 3 : 0;                                 \
        const float* q = rp + (size_t)nk * 32;                                 \
        A_ = *reinterpret_cast<const float4*>(q);                              \
        B_ = *reinterpret_cast<const float4*>(q + 4);                          \
        int col = (((KK) & 1) * 4 + lg) ^ (l15 & 7);                           \
        _Pragma("unroll")                                                      \
        for (int dt = 0; dt < 8; ++dt) {                                       \
            short8 wf = *reinterpret_cast<const short8*>(                      \
                &w_lds[buf][(dt * 16 + l15) * 64 + col * 8]);                  \
            acc[dt] = __builtin_amdgcn_mfma_f32_16x16x32_bf16(wf, h, acc[dt], 0, 0, 0); \
        }                                                                      \
    }

    // one chunk: stage loads early, 2 KSTEPs, ds_write late, barrier
#define CHUNK(SA_, SB_, TA_, TB_, C_)                                          \
    {                                                                          \
        short8 st0, st1, st2, st3;                                             \
        if ((C_) < 11) {                                                       \
            int ko = ((C_) + 1) * 64;                                          \
            st0 = *reinterpret_cast<const short8*>(wg0 + ko);                  \
            st1 = *reinterpret_cast<const short8*>(wg1 + ko);                  \
            st2 = *reinterpret_cast<const short8*>(wg2 + ko);                  \
            st3 = *reinterpret_cast<const short8*>(wg3 + ko);                  \
        }                                                                      \
        KSTEP(SA_, SB_, 2 * (C_))                                              \
        KSTEP(TA_, TB_, 2 * (C_) + 1)                                          \
        if ((C_) < 11) {                                                       \
            *reinterpret_cast<short8*>(&w_lds[buf ^ 1][lo0]) = st0;            \
            *reinterpret_cast<short8*>(&w_lds[buf ^ 1][lo1]) = st1;            \
            *reinterpret_cast<short8*>(&w_lds[buf ^ 1][lo2]) = st2;            \
            *reinterpret_cast<short8*>(&w_lds[buf ^ 1][lo3]) = st3;            \
        }                                                                      \
        __syncthreads();                                                       \
        buf ^= 1;                                                              \
    }

    // 12 chunks; h-sets rotate with period 3 chunks (A,B / C,A / B,C)
#pragma unroll
    for (int m = 0; m < 4; ++m) {
        CHUNK(aA, bA, aB, bB, 3 * m)
        CHUNK(aC, bC, aA, bA, 3 * m + 1)
        CHUNK(aB, bB, aC, bC, 3 * m + 2)
    }
#undef CHUNK
#undef KSTEP

    // normalize per token + store bf16 (validated epilogue, single token/lane)
    float ss = 0.f;
#pragma unroll
    for (int dt = 0; dt < 8; ++dt) {
        ss += acc[dt][0] * acc[dt][0];
        ss += acc[dt][1] * acc[dt][1];
        ss += acc[dt][2] * acc[dt][2];
        ss += acc[dt][3] * acc[dt][3];
    }
    ss += __shfl_xor(ss, 16, 64);
    ss += __shfl_xor(ss, 32, 64);
    int tok = w * 16 + l15;
    int mk = mask[tok];
    float scale = mk ? (1.0f / fmaxf(sqrtf(ss), 1e-12f)) : 0.0f;
    unsigned short* orow = dst + (size_t)tok * DD + lg * 4;
#pragma unroll
    for (int dt = 0; dt < 8; ++dt) {
        ushort4 o;
        o.x = bf16r(acc[dt][0] * scale);
        o.y = bf16r(acc[dt][1] * scale);
        o.z = bf16r(acc[dt][2] * scale);
        o.w = bf16r(acc[dt][3] * scale);
        *reinterpret_cast<ushort4*>(orow + dt * 16) = o;
    }
}

// ---------------- kernel 3: sim + rowmax per 128-doc chunk (validated) -------
__global__ __launch_bounds__(256) void k_sim(const unsigned short* __restrict__ qe,
                                             const unsigned short* __restrict__ de,
                                             float* __restrict__ partial) {
    __shared__ uint4 qs[SQL * 16];     // 32KB
    __shared__ uint4 dsm[SQL * 16];    // 32KB (128 doc rows)
    __shared__ float bm[4][SQL];

    int b = blockIdx.x >> 3;
    int c = blockIdx.x & 7;

    const uint4* qg = reinterpret_cast<const uint4*>(qe + (size_t)b * SQL * DD);
    for (int idx = threadIdx.x; idx < SQL * 16; idx += 256) {
        int row = idx >> 4, ch = idx & 15;
        qs[row * 16 + (ch ^ (row & 7))] = qg[idx];
    }
    const uint4* dg = reinterpret_cast<const uint4*>(de + ((size_t)b * SDL + (size_t)c * 128) * DD);
    for (int idx = threadIdx.x; idx < SQL * 16; idx += 256) {
        int row = idx >> 4, ch = idx & 15;
        dsm[row * 16 + (ch ^ (row & 7))] = dg[idx];
    }
    __syncthreads();

    int lane = threadIdx.x & 63;
    int w = threadIdx.x >> 6;
    int l15 = lane & 15;
    int lg = lane >> 4;

    float rmax[8][4];
#pragma unroll
    for (int i = 0; i < 8; ++i)
#pragma unroll
        for (int r = 0; r < 4; ++r) rmax[i][r] = -3.4e38f;

    for (int i = 0; i < 8; ++i) {
        short8 a[4];
        int arow = i * 16 + l15;
#pragma unroll
        for (int ks = 0; ks < 4; ++ks) {
            int ch = ks * 4 + lg;
            a[ks] = *reinterpret_cast<const short8*>(&qs[arow * 16 + (ch ^ (arow & 7))]);
        }
#pragma unroll
        for (int jj = 0; jj < 2; ++jj) {
            int drow = (w * 2 + jj) * 16 + l15;
            f32x4 accv = (f32x4){0.f, 0.f, 0.f, 0.f};
#pragma unroll
            for (int ks = 0; ks < 4; ++ks) {
                int ch = ks * 4 + lg;
                short8 bf = *reinterpret_cast<const short8*>(&dsm[drow * 16 + (ch ^ (drow & 7))]);
                accv = __builtin_amdgcn_mfma_f32_16x16x32_bf16(a[ks], bf, accv, 0, 0, 0);
            }
#pragma unroll
            for (int r = 0; r < 4; ++r) rmax[i][r] = fmaxf(rmax[i][r], accv[r]);
        }
    }

#pragma unroll
    for (int i = 0; i < 8; ++i) {
#pragma unroll
        for (int r = 0; r < 4; ++r) {
            float v = rmax[i][r];
            v = fmaxf(v, __shfl_xor(v, 1, 64));
            v = fmaxf(v, __shfl_xor(v, 2, 64));
            v = fmaxf(v, __shfl_xor(v, 4, 64));
            v = fmaxf(v, __shfl_xor(v, 8, 64));
            if (l15 == 0) bm[w][i * 16 + lg * 4 + r] = v;
        }
    }
    __syncthreads();

    if (threadIdx.x < SQL) {
        int sq = threadIdx.x;
        float m = fmaxf(fmaxf(bm[0][sq], bm[1][sq]), fmaxf(bm[2][sq], bm[3][sq]));
        partial[((size_t)b * 8 + c) * SQL + sq] = m;
    }
}

// ---------------- kernel 4: max over 8 chunks, sum over sq (validated) -------
__global__ __launch_bounds__(128) void k_reduce(const float* __restrict__ partial,
                                                float* __restrict__ out) {
    int b = blockIdx.x;
    int sq = threadIdx.x;  // 128 threads
    const float* p = partial + (size_t)b * 8 * SQL;
    float m = -3.4e38f;
#pragma unroll
    for (int k = 0; k < 8; ++k) m = fmaxf(m, p[k * SQL + sq]);
    float s = m;
    s += __shfl_xor(s, 1, 64);
    s += __shfl_xor(s, 2, 64);
    s += __shfl_xor(s, 4, 64);
    s += __shfl_xor(s, 8, 64);
    s += __shfl_xor(s, 16, 64);
    s += __shfl_xor(s, 32, 64);
    __shared__ float tmp[2];
    int lane = threadIdx.x & 63;
    int wv = threadIdx.x >> 6;
    if (lane == 0) tmp[wv] = s;
    __syncthreads();
    if (threadIdx.x == 0) out[b] = tmp[0] + tmp[1];
}

extern "C" void kernel_launch(void* const* d_in, const int* in_sizes, int n_in,
                              void* d_out, int out_size, void* d_ws, size_t ws_size,
                              hipStream_t stream) {
    const float* qh = (const float*)d_in[0];
    const int* qm = (const int*)d_in[1];
    const float* dh = (const float*)d_in[2];
    const int* dm = (const int*)d_in[3];
    const float* W = (const float*)d_in[4];
    float* out = (float*)d_out;

    char* ws = (char*)d_ws;
    // layout: Wb [0,196608) | qe [196608, 2293760) | de [2293760, 19070976) | partial [19070976, 19333120)
    unsigned short* Wb = (unsigned short*)(ws);
    unsigned short* qe = (unsigned short*)(ws + 196608);
    unsigned short* de = (unsigned short*)(ws + 2293760);
    float* partial = (float*)(ws + 19070976);

    hipLaunchKernelGGL(k_wconv, dim3(96), dim3(256), 0, stream, W, Wb);
    hipLaunchKernelGGL(k_project, dim3(NB * 18), dim3(256), 0, stream,
                       qh, qm, dh, dm, Wb, qe, de);
    hipLaunchKernelGGL(k_sim, dim3(NB * 8), dim3(256), 0, stream, qe, de, partial);
    hipLaunchKernelGGL(k_reduce, dim3(NB), dim3(128), 0, stream, partial, out);
}